// Round 13
// baseline (67.229 us; speedup 1.0000x reference)
//
#include <hip/hip_runtime.h>

typedef float    v4f    __attribute__((ext_vector_type(4)));
typedef __fp16   f16x8  __attribute__((ext_vector_type(8)));
typedef __fp16   f16x2  __attribute__((ext_vector_type(2)));
typedef short    bf16x8 __attribute__((ext_vector_type(8)));
typedef unsigned u32x4  __attribute__((ext_vector_type(4)));
typedef unsigned short u16;

__constant__ unsigned char c_pair[28] = {
  1,2,3,4,5,6,7, 10,11,12,13,14,15, 19,20,21,22,23, 28,29,30,31, 37,38,39, 46,47, 55
};

static __device__ __forceinline__ unsigned asu(float f){ union{float f;unsigned u;}v; v.f=f; return v.u; }
static __device__ __forceinline__ float lo2f(unsigned d){ union{unsigned u;float f;}v; v.u = d<<16; return v.f; }
static __device__ __forceinline__ float hi2f(unsigned d){ union{unsigned u;float f;}v; v.u = d & 0xffff0000u; return v.f; }
// bf16 pack (fallback kernel only)
static __device__ __forceinline__ unsigned pkt(float lo, float hi){
  return __builtin_amdgcn_perm(asu(hi), asu(lo), 0x07060302u);
}
// f16 pack: one v_cvt_pkrtz_f16_f32
static __device__ __forceinline__ unsigned pkh(float lo, float hi){
  union { f16x2 h; unsigned u; } v;
  v.h = __builtin_amdgcn_cvt_pkrtz(lo, hi);
  return v.u;
}

// ---------------- ws image layout (all f16, 2B elems) ----
#define WS_W1AB 0
#define WS_W1G  65536
#define WS_W2   98304
#define WS_GP   114688
#define WS_NEED 4308992

// ================= prep kernels =================
__global__ __launch_bounds__(1024)
void prep_weights(const float* __restrict__ W1, const float* __restrict__ W2, char* __restrict__ ws)
{
  const int idx = blockIdx.x * 1024 + threadIdx.x;   // 28 blocks * 1024 = 28672
  if (idx < 16384) {
    const int c = idx >> 6, kp = idx & 63;
    const int part = c >> 7, cc = c & 127;
    const float a  = W1[(size_t)(part * 128 + 2 * kp) * 128 + cc];
    const float b_ = W1[(size_t)(part * 128 + 2 * kp + 1) * 128 + cc];
    *(unsigned*)(ws + WS_W1AB + (size_t)c * 256 + ((kp * 4) ^ ((c & 7) << 4))) = pkh(a, b_);
  } else if (idx < 24576) {
    const int j = idx - 16384, c = j >> 6, kp = j & 63;
    const float a  = W1[(size_t)(256 + 2 * kp) * 128 + c];
    const float b_ = W1[(size_t)(256 + 2 * kp + 1) * 128 + c];
    *(unsigned*)(ws + WS_W1G + (size_t)c * 256 + ((kp * 4) ^ ((c & 7) << 4))) = pkh(a, b_);
  } else if (idx < 28672) {
    const int j = idx - 24576, c = j >> 6, kp = j & 63;
    const float a  = W2[(size_t)(2 * kp) * 64 + c];
    const float b_ = W2[(size_t)(2 * kp + 1) * 64 + c];
    *(unsigned*)(ws + WS_W2 + (size_t)c * 256 + ((kp * 4) ^ ((c & 7) << 4))) = pkh(a, b_);
  }
}

__global__ __launch_bounds__(256)
void prep_gp(const float* __restrict__ glob, const float* __restrict__ b1, char* __restrict__ ws)
{
  __shared__ __align__(16) char sm[65536];   // [0,32K) glob tile f16 swz; [32K,64K) W1gT
  const int tid = threadIdx.x;
  const int bb0 = blockIdx.x * 128;          // 128 blocks x 128 batches
  for (int i = tid; i < 2048; i += 256) {
    const u32x4 v = *(const u32x4*)(ws + WS_W1G + i * 16);
    *(u32x4*)(sm + 32768 + i * 16) = v;
  }
  for (int i = tid; i < 4096; i += 256) {
    const int r = i >> 5, q = i & 31;
    const float4 f = *(const float4*)(glob + (size_t)(bb0 + r) * 128 + q * 4);
    int2 w; w.x = (int)pkh(f.x, f.y); w.y = (int)pkh(f.z, f.w);
    *(int2*)(sm + r * 256 + ((q * 8) ^ ((r & 7) << 4))) = w;
  }
  __syncthreads();
  const int wave = tid >> 6, lane = tid & 63, lrow = lane & 15, lko = (lane >> 4) * 8;
  float b1c[8];
#pragma unroll
  for (int nt = 0; nt < 8; ++nt) b1c[nt] = b1[nt * 16 + lrow];
  const v4f vzero = {0.f, 0.f, 0.f, 0.f};
  v4f acc[2][8];
#pragma unroll
  for (int mt = 0; mt < 2; ++mt)
#pragma unroll
    for (int nt = 0; nt < 8; ++nt) acc[mt][nt] = vzero;
#pragma unroll
  for (int ks = 0; ks < 4; ++ks) {
    const int kb = (ks * 32 + lko) * 2;
    f16x8 af[2];
#pragma unroll
    for (int mt = 0; mt < 2; ++mt) {
      const int r = wave * 32 + mt * 16 + lrow;
      af[mt] = *(const f16x8*)(sm + r * 256 + (kb ^ ((r & 7) << 4)));
    }
#pragma unroll
    for (int nt = 0; nt < 8; ++nt) {
      const int c = nt * 16 + lrow;
      const f16x8 bfr = *(const f16x8*)(sm + 32768 + c * 256 + (kb ^ ((c & 7) << 4)));
#pragma unroll
      for (int mt = 0; mt < 2; ++mt)
        acc[mt][nt] = __builtin_amdgcn_mfma_f32_16x16x32_f16(af[mt], bfr, acc[mt][nt], 0, 0, 0);
    }
  }
#pragma unroll
  for (int mt = 0; mt < 2; ++mt)
#pragma unroll
    for (int nt = 0; nt < 8; ++nt) {
      const int c = nt * 16 + lrow;
#pragma unroll
      for (int rg = 0; rg < 4; ++rg) {
        const int m = wave * 32 + mt * 16 + (lane >> 4) * 4 + rg;
        const int batch = bb0 + m;
        const int g = batch >> 4, q = m & 15;
        *(u16*)(ws + WS_GP + (size_t)g * 4096 + q * 256 + ((c * 2) ^ ((q & 7) << 4))) =
            (u16)pkh(acc[mt][nt][rg] + b1c[nt], 0.0f);
      }
    }
}

// ================= main kernel =================
// PERSISTENT: 768 blocks (3/CU, all resident) x 512 threads; grid-stride over 2048
// 8-batch tiles. LDS unchanged (53760 B). Phase-1 MFMA operands SWAPPED so the
// proj write is 8x ds_write_b64 (vector) instead of 32x ds_write_b16. Next tile's
// node data prefetched into registers during phase 2.
#define M3_PA   0
#define M3_PB   16384
#define M3_ND   32768    // node f16 swz in phase 1; W2T in phase 2
#define M3_GP   49152
#define M3_V    53248    // b2 f32[64] | W3 f32[64]
#define M3_SMEM 53760
#define NTILES  2048
#define PBLK    768

__global__ __launch_bounds__(512)
void docking_main(const float* __restrict__ node, const int* __restrict__ dmask,
                  const float* __restrict__ b2, const float* __restrict__ W3,
                  const float* __restrict__ b3,
                  const char* __restrict__ ws, float* __restrict__ outp)
{
  __shared__ __align__(16) char smem[M3_SMEM];
  const int tid = threadIdx.x;
  const int wave = tid >> 6, lane = tid & 63, lrow = lane & 15, lko = (lane >> 4) * 8;
  const int wm = wave >> 2, wn = wave & 3;       // 2 (M-halves of 32 rows) x 4 (N)
  const float bias3 = *b3;
  const v4f vzero = {0.f, 0.f, 0.f, 0.f};
  const char* wsW = ws + WS_W1AB;
  const int pbase = (wn >= 2) ? M3_PB : M3_PA;

  if (tid < 64)       ((float*)(smem + M3_V))[tid] = b2[tid];
  else if (tid < 128) ((float*)(smem + M3_V))[tid] = W3[tid - 64];

  auto loadND = [&](int tile, float4* pf) {
#pragma unroll
    for (int i = 0; i < 4; ++i) {
      const int idx = tid + i * 512;
      const int r = idx >> 5, q = idx & 31;
      pf[i] = *(const float4*)(node + ((size_t)tile * 64 + r) * 128 + q * 4);
    }
  };

  int tile = blockIdx.x;
  float4 pf[4];
  loadND(tile, pf);

  while (tile < NTILES) {
    const int bb0 = tile * 8;
    // ---- stage node (from prefetch regs) + gp tile ----
#pragma unroll
    for (int i = 0; i < 4; ++i) {
      const int idx = tid + i * 512;
      const int r = idx >> 5, q = idx & 31;
      int2 w; w.x = (int)pkh(pf[i].x, pf[i].y); w.y = (int)pkh(pf[i].z, pf[i].w);
      *(int2*)(smem + M3_ND + r * 256 + ((q * 8) ^ ((r & 7) << 4))) = w;
    }
    {
      const int q = tid >> 6, cp = tid & 63;               // 8 rows x 64 u32
      const int qq = (bb0 & 15) + q;
      union { unsigned u; f16x2 h; } cv;
      cv.u = *(const unsigned*)(ws + WS_GP + ((size_t)(bb0 >> 4)) * 4096
                                + qq * 256 + ((cp * 4) ^ ((qq & 7) << 4)));
      float* gq = (float*)(smem + M3_GP) + q * 128;
      gq[cp * 2] = (float)cv.h[0]; gq[cp * 2 + 1] = (float)cv.h[1];
    }
    __syncthreads();                                   // (A) node + gp visible

    // ---- phase 1: proj GEMM; OPERANDS SWAPPED (rows=c, cols=m) ----
    v4f acc[2][4];
#pragma unroll
    for (int mt = 0; mt < 2; ++mt)
#pragma unroll
      for (int nt = 0; nt < 4; ++nt) acc[mt][nt] = vzero;

#pragma unroll
    for (int ks = 0; ks < 4; ++ks) {
      const int kb = (ks * 32 + lko) * 2;
      f16x8 Bf[4];
#pragma unroll
      for (int nt = 0; nt < 4; ++nt) {
        const int c = wn * 64 + nt * 16 + lrow;
        Bf[nt] = *(const f16x8*)(wsW + c * 256 + (kb ^ ((c & 7) << 4)));
      }
#pragma unroll
      for (int mt = 0; mt < 2; ++mt) {
        const int rr = wm * 32 + mt * 16 + lrow;
        const f16x8 Af = *(const f16x8*)(smem + M3_ND + rr * 256 + (kb ^ ((rr & 7) << 4)));
#pragma unroll
        for (int nt = 0; nt < 4; ++nt)
          acc[mt][nt] = __builtin_amdgcn_mfma_f32_16x16x32_f16(Bf[nt], Af, acc[mt][nt], 0, 0, 0);
      }
    }
    // vectorized proj writes: lane holds m = lrow, 4 consecutive c per (mt,nt)
#pragma unroll
    for (int mt = 0; mt < 2; ++mt) {
      const int m = wm * 32 + mt * 16 + lrow;
#pragma unroll
      for (int nt = 0; nt < 4; ++nt) {
        const int cb = (wn & 1) * 64 + nt * 16 + (lane >> 4) * 4;
        float v0 = acc[mt][nt][0], v1 = acc[mt][nt][1];
        float v2 = acc[mt][nt][2], v3 = acc[mt][nt][3];
        if (wn >= 2) {
          const float4 g = *(const float4*)((const float*)(smem + M3_GP) + (m >> 3) * 128 + cb);
          v0 += g.x; v1 += g.y; v2 += g.z; v3 += g.w;
        }
        int2 w; w.x = (int)pkh(v0, v1); w.y = (int)pkh(v2, v3);
        *(int2*)(smem + pbase + m * 256 + ((cb * 2) ^ ((m & 7) << 4))) = w;
      }
    }
    __syncthreads();                                   // (B1) node reads done, proj visible

    // ---- stage W2T over the dead node buffer ----
#pragma unroll
    for (int i = 0; i < 2; ++i) {
      const int j = tid + i * 512;
      const u32x4 v = *(const u32x4*)(ws + WS_W2 + j * 16);
      *(u32x4*)(smem + M3_ND + j * 16) = v;
    }
    __syncthreads();                                   // (B2) W2T visible

    // ---- prefetch next tile's node (hidden under phase 2) ----
    const int ntile = tile + PBLK;
    if (ntile < NTILES) loadND(ntile, pf);

    // ---- phase 2: pair MLP (14 tiles of 16 pair-rows over 8 waves) ----
    const float* sV = (const float*)(smem + M3_V);
    for (int t = wave; t < 14; t += 8) {
      const int r  = t * 16 + lrow;                    // 0..223
      const int bb = (r * 9363) >> 18;                 // r/28 for r<2340
      const int p  = r - bb * 28;
      const unsigned pr8 = c_pair[p];
      const int mi = bb * 8 + (int)(pr8 >> 3);
      const int mj = bb * 8 + (int)(pr8 & 7);

      v4f acc2[4] = {vzero, vzero, vzero, vzero};
#pragma unroll
      for (int ks = 0; ks < 4; ++ks) {
        const int kb = (ks * 32 + lko) * 2;
        const f16x8 va = *(const f16x8*)(smem + M3_PA + mi * 256 + (kb ^ ((mi & 7) << 4)));
        const f16x8 vb = *(const f16x8*)(smem + M3_PB + mj * 256 + (kb ^ ((mj & 7) << 4)));
        f16x8 h1 = va + vb;                                        // v_pk_add_f16
        h1 = __builtin_elementwise_max(h1, (f16x8)(__fp16)0.0f);   // v_pk_max_f16
#pragma unroll
        for (int nt = 0; nt < 4; ++nt) {
          const int cc = nt * 16 + lrow;
          const f16x8 w2fr = *(const f16x8*)(smem + M3_ND + cc * 256 + (kb ^ ((cc & 7) << 4)));
          acc2[nt] = __builtin_amdgcn_mfma_f32_16x16x32_f16(h1, w2fr, acc2[nt], 0, 0, 0);
        }
      }
      float part[4] = {0.f, 0.f, 0.f, 0.f};
#pragma unroll
      for (int nt = 0; nt < 4; ++nt) {
        const int n = nt * 16 + lrow;
        const float b2v = sV[n], w3v = sV[64 + n];
#pragma unroll
        for (int rg = 0; rg < 4; ++rg)
          part[rg] += fmaxf(acc2[nt][rg] + b2v, 0.0f) * w3v;
      }
#pragma unroll
      for (int mk = 1; mk < 16; mk <<= 1)
#pragma unroll
        for (int rg = 0; rg < 4; ++rg) part[rg] += __shfl_xor(part[rg], mk, 16);

      if ((lane & 15) == 0) {
        const int rb = t * 16 + (lane >> 4) * 4;
#pragma unroll
        for (int rg = 0; rg < 4; ++rg) {
          const int rr = rb + rg;
          const int b2_ = (rr * 9363) >> 18;
          const int p2  = rr - b2_ * 28;
          const size_t o = (size_t)(bb0 + b2_) * 28 + p2;
          outp[o] = dmask[o] ? (part[rg] + bias3) : -1.0e9f;
        }
      }
    }

    tile = ntile;
    if (tile < NTILES) __syncthreads();                // (C) protect LDS before restage
  }
}

// ================= fallback (proven R3 fused kernel, bf16) =================
#define F_THREADS 512
#define F_NB      8
#define F_OFF_A    0
#define F_OFF_GL   16384
#define F_OFF_SB   20480
#define F_OFF_W2   53248
#define F_OFF_B1V  69632
#define F_OFF_B2V  70144
#define F_OFF_W3V  70400
#define F_SMEM     70656

__global__ __launch_bounds__(F_THREADS, 4)
void docking_fused(const float* __restrict__ node, const float* __restrict__ glob,
                   const int* __restrict__ dmask,
                   const float* __restrict__ W1, const float* __restrict__ b1,
                   const float* __restrict__ W2, const float* __restrict__ b2,
                   const float* __restrict__ W3, const float* __restrict__ b3,
                   float* __restrict__ outp)
{
  __shared__ __align__(16) char smem[F_SMEM];
  const int tid = threadIdx.x;
  const int bb0 = blockIdx.x * F_NB;
  const size_t nrow0 = (size_t)bb0 * 8;
  const float bias3 = *b3;

  if (tid < 128)      ((float*)(smem + F_OFF_B1V))[tid]       = b1[tid];
  else if (tid < 192) ((float*)(smem + F_OFF_B2V))[tid - 128] = b2[tid - 128];
  else if (tid < 256) ((float*)(smem + F_OFF_W3V))[tid - 192] = W3[tid - 192];

  for (int idx = tid; idx < 64 * 32; idx += F_THREADS) {
    const int r = idx >> 5, q = idx & 31;
    const float4 f = *(const float4*)(node + (nrow0 + (size_t)r) * 128 + q * 4);
    int2 w; w.x = (int)pkt(f.x, f.y); w.y = (int)pkt(f.z, f.w);
    *(int2*)(smem + F_OFF_A + r * 256 + ((q * 8) ^ ((r & 7) << 4))) = w;
  }
  for (int idx = tid; idx < 16 * 32; idx += F_THREADS) {
    const int r = idx >> 5, q = idx & 31;
    float4 f = make_float4(0.f, 0.f, 0.f, 0.f);
    if (r < F_NB) f = *(const float4*)(glob + (size_t)(bb0 + r) * 128 + q * 4);
    int2 w; w.x = (int)pkt(f.x, f.y); w.y = (int)pkt(f.z, f.w);
    *(int2*)(smem + F_OFF_GL + r * 256 + ((q * 8) ^ ((r & 7) << 4))) = w;
  }
  for (int idx = tid; idx < 4096; idx += F_THREADS) {
    const int cl = idx & 7, kl = (idx >> 3) & 7, ch = (idx >> 6) & 7, kh = idx >> 9;
    const int c = cl | (ch << 3), kp = kl | (kh << 3);
    const float a  = W2[(size_t)(2 * kp) * 64 + c];
    const float b_ = W2[(size_t)(2 * kp + 1) * 64 + c];
    *(unsigned*)(smem + F_OFF_W2 + c * 256 + ((kp * 4) ^ ((c & 7) << 4))) = pkt(a, b_);
  }
  auto stageB = [&](int rowOff) {
    for (int idx = tid; idx < 8192; idx += F_THREADS) {
      const int cl = idx & 7, kl = (idx >> 3) & 7, ch = (idx >> 6) & 15, kh = idx >> 10;
      const int c = cl | (ch << 3), kp = kl | (kh << 3);
      const float a  = W1[(size_t)(rowOff + 2 * kp) * 128 + c];
      const float b_ = W1[(size_t)(rowOff + 2 * kp + 1) * 128 + c];
      *(unsigned*)(smem + F_OFF_SB + c * 256 + ((kp * 4) ^ ((c & 7) << 4))) = pkt(a, b_);
    }
  };
  stageB(0);
  __syncthreads();

  const int wave = tid >> 6, lane = tid & 63;
  const int lrow = lane & 15;
  const int lko  = (lane >> 4) * 8;
  const int wmt = wave >> 1, wnh = wave & 1;
  const v4f vzero = {0.f, 0.f, 0.f, 0.f};

  bf16x8 af[4];
#pragma unroll
  for (int ks = 0; ks < 4; ++ks) {
    const int r = wmt * 16 + lrow;
    af[ks] = *(const bf16x8*)(smem + F_OFF_A + r * 256 + (((ks * 32 + lko) * 2) ^ ((r & 7) << 4)));
  }
  v4f acc_a[4] = {vzero, vzero, vzero, vzero};
#pragma unroll
  for (int ks = 0; ks < 4; ++ks) {
    const int kb = (ks * 32 + lko) * 2;
#pragma unroll
    for (int nt = 0; nt < 4; ++nt) {
      const int c = wnh * 64 + nt * 16 + lrow;
      const bf16x8 bfr = *(const bf16x8*)(smem + F_OFF_SB + c * 256 + (kb ^ ((c & 7) << 4)));
      acc_a[nt] = __builtin_amdgcn_mfma_f32_16x16x32_bf16(af[ks], bfr, acc_a[nt], 0, 0, 0);
    }
  }
  __syncthreads();
  stageB(128);
  __syncthreads();
  v4f acc_b[4] = {vzero, vzero, vzero, vzero};
#pragma unroll
  for (int ks = 0; ks < 4; ++ks) {
    const int kb = (ks * 32 + lko) * 2;
#pragma unroll
    for (int nt = 0; nt < 4; ++nt) {
      const int c = wnh * 64 + nt * 16 + lrow;
      const bf16x8 bfr = *(const bf16x8*)(smem + F_OFF_SB + c * 256 + (kb ^ ((c & 7) << 4)));
      acc_b[nt] = __builtin_amdgcn_mfma_f32_16x16x32_bf16(af[ks], bfr, acc_b[nt], 0, 0, 0);
    }
  }
  __syncthreads();
  stageB(256);
  __syncthreads();
  v4f accg = vzero;
#pragma unroll
  for (int ks = 0; ks < 4; ++ks) {
    const int kb = (ks * 32 + lko) * 2;
    const bf16x8 ag = *(const bf16x8*)(smem + F_OFF_GL + lrow * 256 + (kb ^ ((lrow & 7) << 4)));
    const int cg = wave * 16 + lrow;
    const bf16x8 bg = *(const bf16x8*)(smem + F_OFF_SB + cg * 256 + (kb ^ ((cg & 7) << 4)));
    accg = __builtin_amdgcn_mfma_f32_16x16x32_bf16(ag, bg, accg, 0, 0, 0);
  }
  __syncthreads();
  {
    const int rgb = (lane >> 4) * 4;
#pragma unroll
    for (int nt = 0; nt < 4; ++nt) {
      const int c = wnh * 64 + nt * 16 + lrow;
#pragma unroll
      for (int rg = 0; rg < 4; ++rg) {
        const int m = wmt * 16 + rgb + rg;
        const int sw = (c * 2) ^ ((m & 7) << 4);
        *(u16*)(smem + F_OFF_SB + m * 256 + sw)        = (u16)(asu(acc_a[nt][rg]) >> 16);
        *(u16*)(smem + F_OFF_SB + (64 + m) * 256 + sw) = (u16)(asu(acc_b[nt][rg]) >> 16);
      }
    }
    const int cg = wave * 16 + lrow;
    const float b1c = ((const float*)(smem + F_OFF_B1V))[cg];
#pragma unroll
    for (int rg = 0; rg < 4; ++rg) {
      const int bbr = rgb + rg;
      if (bbr < F_NB)
        *(u16*)(smem + F_OFF_A + bbr * 256 + ((cg * 2) ^ ((bbr & 7) << 4))) =
            (u16)(asu(accg[rg] + b1c) >> 16);
    }
  }
  __syncthreads();

  float b2n[4], w3n[4];
#pragma unroll
  for (int nt = 0; nt < 4; ++nt) {
    const int n = nt * 16 + lrow;
    b2n[nt] = ((const float*)(smem + F_OFF_B2V))[n];
    w3n[nt] = ((const float*)(smem + F_OFF_W3V))[n];
  }
  for (int t = wave; t < 14; t += 8) {
    const int r  = t * 16 + lrow;
    const int bb = (r * 9363) >> 18;
    const int p  = r - bb * 28;
    const unsigned pr8 = c_pair[p];
    const int mi = bb * 8 + (int)(pr8 >> 3);
    const int mj = 64 + bb * 8 + (int)(pr8 & 7);
    v4f acc2[4] = {vzero, vzero, vzero, vzero};
#pragma unroll
    for (int ks = 0; ks < 4; ++ks) {
      const int kb = (ks * 32 + lko) * 2;
      const u32x4 va = *(const u32x4*)(smem + F_OFF_SB + mi * 256 + (kb ^ ((mi & 7) << 4)));
      const u32x4 vb = *(const u32x4*)(smem + F_OFF_SB + mj * 256 + (kb ^ ((mj & 7) << 4)));
      const u32x4 vg = *(const u32x4*)(smem + F_OFF_A  + bb * 256 + (kb ^ ((bb & 7) << 4)));
      u32x4 a2;
#pragma unroll
      for (int w = 0; w < 4; ++w) {
        const float lo = fmaxf(lo2f(va[w]) + lo2f(vb[w]) + lo2f(vg[w]), 0.0f);
        const float hi = fmaxf(hi2f(va[w]) + hi2f(vb[w]) + hi2f(vg[w]), 0.0f);
        a2[w] = pkt(lo, hi);
      }
      union { u32x4 u; bf16x8 h; } cv; cv.u = a2;
#pragma unroll
      for (int nt = 0; nt < 4; ++nt) {
        const int c = nt * 16 + lrow;
        const bf16x8 w2fr = *(const bf16x8*)(smem + F_OFF_W2 + c * 256 + (kb ^ ((c & 7) << 4)));
        acc2[nt] = __builtin_amdgcn_mfma_f32_16x16x32_bf16(cv.h, w2fr, acc2[nt], 0, 0, 0);
      }
    }
    float part[4] = {0.f, 0.f, 0.f, 0.f};
#pragma unroll
    for (int nt = 0; nt < 4; ++nt)
#pragma unroll
      for (int rg = 0; rg < 4; ++rg)
        part[rg] += fmaxf(acc2[nt][rg] + b2n[nt], 0.0f) * w3n[nt];
#pragma unroll
    for (int mk = 1; mk < 16; mk <<= 1)
#pragma unroll
      for (int rg = 0; rg < 4; ++rg) part[rg] += __shfl_xor(part[rg], mk, 16);
    if ((lane & 15) == 0) {
      const int rb = t * 16 + (lane >> 4) * 4;
#pragma unroll
      for (int rg = 0; rg < 4; ++rg) {
        const int rr = rb + rg;
        const int b2_ = (rr * 9363) >> 18;
        const int p2  = rr - b2_ * 28;
        const size_t o = (size_t)(bb0 + b2_) * 28 + p2;
        outp[o] = dmask[o] ? (part[rg] + bias3) : -1.0e9f;
      }
    }
  }
}

extern "C" void kernel_launch(void* const* d_in, const int* in_sizes, int n_in,
                              void* d_out, int out_size, void* d_ws, size_t ws_size,
                              hipStream_t stream) {
  (void)in_sizes; (void)n_in; (void)out_size;
  const float* node = (const float*)d_in[0];
  const float* glob = (const float*)d_in[1];
  const int* dmsk   = (const int*)d_in[3];   // bool -> int32 on upload
  const float* W1 = (const float*)d_in[5];
  const float* b1 = (const float*)d_in[6];
  const float* W2 = (const float*)d_in[7];
  const float* b2 = (const float*)d_in[8];
  const float* W3 = (const float*)d_in[9];
  const float* b3 = (const float*)d_in[10];
  float* outp = (float*)d_out;

  if (ws_size >= (size_t)WS_NEED) {
    char* ws = (char*)d_ws;
    prep_weights<<<28, 1024, 0, stream>>>(W1, W2, ws);
    prep_gp<<<128, 256, 0, stream>>>(glob, b1, ws);
    docking_main<<<PBLK, 512, 0, stream>>>(node, dmsk, b2, W3, b3, ws, outp);
  } else {
    docking_fused<<<16384 / F_NB, F_THREADS, 0, stream>>>(node, glob, dmsk, W1, b1, W2, b2, W3, b3, outp);
  }
}

// Round 14
// 63.025 us; speedup vs baseline: 1.0667x; 1.0667x over previous
//
#include <hip/hip_runtime.h>

typedef float    v4f    __attribute__((ext_vector_type(4)));
typedef __fp16   f16x8  __attribute__((ext_vector_type(8)));
typedef __fp16   f16x2  __attribute__((ext_vector_type(2)));
typedef short    bf16x8 __attribute__((ext_vector_type(8)));
typedef unsigned u32x4  __attribute__((ext_vector_type(4)));
typedef unsigned short u16;

__constant__ unsigned char c_pair[28] = {
  1,2,3,4,5,6,7, 10,11,12,13,14,15, 19,20,21,22,23, 28,29,30,31, 37,38,39, 46,47, 55
};

static __device__ __forceinline__ unsigned asu(float f){ union{float f;unsigned u;}v; v.f=f; return v.u; }
static __device__ __forceinline__ float lo2f(unsigned d){ union{unsigned u;float f;}v; v.u = d<<16; return v.f; }
static __device__ __forceinline__ float hi2f(unsigned d){ union{unsigned u;float f;}v; v.u = d & 0xffff0000u; return v.f; }
// bf16 pack (fallback kernel only)
static __device__ __forceinline__ unsigned pkt(float lo, float hi){
  return __builtin_amdgcn_perm(asu(hi), asu(lo), 0x07060302u);
}
// f16 pack: one v_cvt_pkrtz_f16_f32
static __device__ __forceinline__ unsigned pkh(float lo, float hi){
  union { f16x2 h; unsigned u; } v;
  v.h = __builtin_amdgcn_cvt_pkrtz(lo, hi);
  return v.u;
}

// ---------------- ws image layout (all f16, 2B elems) ----
#define WS_W1AB 0
#define WS_W1G  65536
#define WS_W2   98304
#define WS_GP   114688
#define WS_NEED 4308992

// ================= prep kernels =================
__global__ __launch_bounds__(1024)
void prep_weights(const float* __restrict__ W1, const float* __restrict__ W2, char* __restrict__ ws)
{
  const int idx = blockIdx.x * 1024 + threadIdx.x;   // 28 blocks * 1024 = 28672
  if (idx < 16384) {
    const int c = idx >> 6, kp = idx & 63;
    const int part = c >> 7, cc = c & 127;
    const float a  = W1[(size_t)(part * 128 + 2 * kp) * 128 + cc];
    const float b_ = W1[(size_t)(part * 128 + 2 * kp + 1) * 128 + cc];
    *(unsigned*)(ws + WS_W1AB + (size_t)c * 256 + ((kp * 4) ^ ((c & 7) << 4))) = pkh(a, b_);
  } else if (idx < 24576) {
    const int j = idx - 16384, c = j >> 6, kp = j & 63;
    const float a  = W1[(size_t)(256 + 2 * kp) * 128 + c];
    const float b_ = W1[(size_t)(256 + 2 * kp + 1) * 128 + c];
    *(unsigned*)(ws + WS_W1G + (size_t)c * 256 + ((kp * 4) ^ ((c & 7) << 4))) = pkh(a, b_);
  } else if (idx < 28672) {
    const int j = idx - 24576, c = j >> 6, kp = j & 63;
    const float a  = W2[(size_t)(2 * kp) * 64 + c];
    const float b_ = W2[(size_t)(2 * kp + 1) * 64 + c];
    *(unsigned*)(ws + WS_W2 + (size_t)c * 256 + ((kp * 4) ^ ((c & 7) << 4))) = pkh(a, b_);
  }
}

__global__ __launch_bounds__(256)
void prep_gp(const float* __restrict__ glob, const float* __restrict__ b1, char* __restrict__ ws)
{
  __shared__ __align__(16) char sm[65536];   // [0,32K) glob tile f16 swz; [32K,64K) W1gT
  const int tid = threadIdx.x;
  const int bb0 = blockIdx.x * 128;          // 128 blocks x 128 batches
  for (int i = tid; i < 2048; i += 256) {
    const u32x4 v = *(const u32x4*)(ws + WS_W1G + i * 16);
    *(u32x4*)(sm + 32768 + i * 16) = v;
  }
  for (int i = tid; i < 4096; i += 256) {
    const int r = i >> 5, q = i & 31;
    const float4 f = *(const float4*)(glob + (size_t)(bb0 + r) * 128 + q * 4);
    int2 w; w.x = (int)pkh(f.x, f.y); w.y = (int)pkh(f.z, f.w);
    *(int2*)(sm + r * 256 + ((q * 8) ^ ((r & 7) << 4))) = w;
  }
  __syncthreads();
  const int wave = tid >> 6, lane = tid & 63, lrow = lane & 15, lko = (lane >> 4) * 8;
  float b1c[8];
#pragma unroll
  for (int nt = 0; nt < 8; ++nt) b1c[nt] = b1[nt * 16 + lrow];
  const v4f vzero = {0.f, 0.f, 0.f, 0.f};
  v4f acc[2][8];
#pragma unroll
  for (int mt = 0; mt < 2; ++mt)
#pragma unroll
    for (int nt = 0; nt < 8; ++nt) acc[mt][nt] = vzero;
#pragma unroll
  for (int ks = 0; ks < 4; ++ks) {
    const int kb = (ks * 32 + lko) * 2;
    f16x8 af[2];
#pragma unroll
    for (int mt = 0; mt < 2; ++mt) {
      const int r = wave * 32 + mt * 16 + lrow;
      af[mt] = *(const f16x8*)(sm + r * 256 + (kb ^ ((r & 7) << 4)));
    }
#pragma unroll
    for (int nt = 0; nt < 8; ++nt) {
      const int c = nt * 16 + lrow;
      const f16x8 bfr = *(const f16x8*)(sm + 32768 + c * 256 + (kb ^ ((c & 7) << 4)));
#pragma unroll
      for (int mt = 0; mt < 2; ++mt)
        acc[mt][nt] = __builtin_amdgcn_mfma_f32_16x16x32_f16(af[mt], bfr, acc[mt][nt], 0, 0, 0);
    }
  }
#pragma unroll
  for (int mt = 0; mt < 2; ++mt)
#pragma unroll
    for (int nt = 0; nt < 8; ++nt) {
      const int c = nt * 16 + lrow;
#pragma unroll
      for (int rg = 0; rg < 4; ++rg) {
        const int m = wave * 32 + mt * 16 + (lane >> 4) * 4 + rg;
        const int batch = bb0 + m;
        const int g = batch >> 4, q = m & 15;
        *(u16*)(ws + WS_GP + (size_t)g * 4096 + q * 256 + ((c * 2) ^ ((q & 7) << 4))) =
            (u16)pkh(acc[mt][nt][rg] + b1c[nt], 0.0f);
      }
    }
}

// ================= main kernel =================
// 2048 blocks x 512 threads (8 waves); each block = ONE 8-batch tile (64 node rows).
// LDS = ND(16K node) + Pa(16K) + Pb'(16K) + gp(4K) + V(512) = 53760 B -> 3 blocks/CU.
// Phase 1: swapped-operand MFMA (rows=c, cols=m) -> proj writes are vector ds_write_b64.
// Phase 2: W2 fragments read DIRECTLY from ws via L2 (no W2 staging, no 3rd barrier).
#define M3_ND   0
#define M3_PA   16384
#define M3_PB   32768
#define M3_GP   49152
#define M3_V    53248    // b2 f32[64] | W3 f32[64]
#define M3_SMEM 53760

__global__ __launch_bounds__(512)
void docking_main(const float* __restrict__ node, const int* __restrict__ dmask,
                  const float* __restrict__ b2, const float* __restrict__ W3,
                  const float* __restrict__ b3,
                  const char* __restrict__ ws, float* __restrict__ outp)
{
  __shared__ __align__(16) char smem[M3_SMEM];
  const int tid = threadIdx.x;
  const int wave = tid >> 6, lane = tid & 63, lrow = lane & 15, lko = (lane >> 4) * 8;
  const int wm = wave >> 2, wn = wave & 3;       // 2 (M-halves of 32 rows) x 4 (N)
  const int bb0 = blockIdx.x * 8;
  const float bias3 = *b3;
  const v4f vzero = {0.f, 0.f, 0.f, 0.f};
  const char* wsW = ws + WS_W1AB;
  const char* wsW2 = ws + WS_W2;
  const int pbase = (wn >= 2) ? M3_PB : M3_PA;

  // ---- stage node tile (coalesced) + gp tile + consts ----
  for (int idx = tid; idx < 64 * 32; idx += 512) {       // 4 iters
    const int r = idx >> 5, q = idx & 31;
    const float4 f = *(const float4*)(node + ((size_t)bb0 * 8 + r) * 128 + q * 4);
    int2 w; w.x = (int)pkh(f.x, f.y); w.y = (int)pkh(f.z, f.w);
    *(int2*)(smem + M3_ND + r * 256 + ((q * 8) ^ ((r & 7) << 4))) = w;
  }
  {
    const int q = tid >> 6, cp = tid & 63;               // 8 rows x 64 u32
    const int qq = (bb0 & 15) + q;
    union { unsigned u; f16x2 h; } cv;
    cv.u = *(const unsigned*)(ws + WS_GP + ((size_t)(bb0 >> 4)) * 4096
                              + qq * 256 + ((cp * 4) ^ ((qq & 7) << 4)));
    float* gq = (float*)(smem + M3_GP) + q * 128;
    gq[cp * 2] = (float)cv.h[0]; gq[cp * 2 + 1] = (float)cv.h[1];
  }
  if (tid < 64)       ((float*)(smem + M3_V))[tid] = b2[tid];
  else if (tid < 128) ((float*)(smem + M3_V))[tid] = W3[tid - 64];
  __syncthreads();                                   // (A) node + gp + consts visible

  // ---- phase 1: proj GEMM; operands SWAPPED (acc rows=c, cols=m) ----
  v4f acc[2][4];
#pragma unroll
  for (int mt = 0; mt < 2; ++mt)
#pragma unroll
    for (int nt = 0; nt < 4; ++nt) acc[mt][nt] = vzero;

#pragma unroll
  for (int ks = 0; ks < 4; ++ks) {
    const int kb = (ks * 32 + lko) * 2;
    f16x8 Bf[4];
#pragma unroll
    for (int nt = 0; nt < 4; ++nt) {
      const int c = wn * 64 + nt * 16 + lrow;
      Bf[nt] = *(const f16x8*)(wsW + c * 256 + (kb ^ ((c & 7) << 4)));
    }
#pragma unroll
    for (int mt = 0; mt < 2; ++mt) {
      const int rr = wm * 32 + mt * 16 + lrow;
      const f16x8 Af = *(const f16x8*)(smem + M3_ND + rr * 256 + (kb ^ ((rr & 7) << 4)));
#pragma unroll
      for (int nt = 0; nt < 4; ++nt)
        acc[mt][nt] = __builtin_amdgcn_mfma_f32_16x16x32_f16(Bf[nt], Af, acc[mt][nt], 0, 0, 0);
    }
  }
  // vectorized proj writes: lane holds m = lrow-row, 4 consecutive c per (mt,nt)
#pragma unroll
  for (int mt = 0; mt < 2; ++mt) {
    const int m = wm * 32 + mt * 16 + lrow;
#pragma unroll
    for (int nt = 0; nt < 4; ++nt) {
      const int cb = (wn & 1) * 64 + nt * 16 + (lane >> 4) * 4;
      float v0 = acc[mt][nt][0], v1 = acc[mt][nt][1];
      float v2 = acc[mt][nt][2], v3 = acc[mt][nt][3];
      if (wn >= 2) {
        const float4 g = *(const float4*)((const float*)(smem + M3_GP) + (m >> 3) * 128 + cb);
        v0 += g.x; v1 += g.y; v2 += g.z; v3 += g.w;
      }
      int2 w; w.x = (int)pkh(v0, v1); w.y = (int)pkh(v2, v3);
      *(int2*)(smem + pbase + m * 256 + ((cb * 2) ^ ((m & 7) << 4))) = w;
    }
  }
  __syncthreads();                                   // (B) Pa/Pb' visible

  // ---- phase 2: pair MLP; W2 fragments straight from L2 ----
  const float* sV = (const float*)(smem + M3_V);
  for (int t = wave; t < 14; t += 8) {
    const int r  = t * 16 + lrow;                    // 0..223
    const int bb = (r * 9363) >> 18;                 // r/28 for r<2340
    const int p  = r - bb * 28;
    const unsigned pr8 = c_pair[p];
    const int mi = bb * 8 + (int)(pr8 >> 3);
    const int mj = bb * 8 + (int)(pr8 & 7);

    v4f acc2[4] = {vzero, vzero, vzero, vzero};
#pragma unroll
    for (int ks = 0; ks < 4; ++ks) {
      const int kb = (ks * 32 + lko) * 2;
      const f16x8 va = *(const f16x8*)(smem + M3_PA + mi * 256 + (kb ^ ((mi & 7) << 4)));
      const f16x8 vb = *(const f16x8*)(smem + M3_PB + mj * 256 + (kb ^ ((mj & 7) << 4)));
      f16x8 h1 = va + vb;                                        // v_pk_add_f16
      h1 = __builtin_elementwise_max(h1, (f16x8)(__fp16)0.0f);   // v_pk_max_f16
#pragma unroll
      for (int nt = 0; nt < 4; ++nt) {
        const int cc = nt * 16 + lrow;
        const f16x8 w2fr = *(const f16x8*)(wsW2 + cc * 256 + (kb ^ ((cc & 7) << 4)));
        acc2[nt] = __builtin_amdgcn_mfma_f32_16x16x32_f16(h1, w2fr, acc2[nt], 0, 0, 0);
      }
    }
    float part[4] = {0.f, 0.f, 0.f, 0.f};
#pragma unroll
    for (int nt = 0; nt < 4; ++nt) {
      const int n = nt * 16 + lrow;
      const float b2v = sV[n], w3v = sV[64 + n];
#pragma unroll
      for (int rg = 0; rg < 4; ++rg)
        part[rg] += fmaxf(acc2[nt][rg] + b2v, 0.0f) * w3v;
    }
#pragma unroll
    for (int mk = 1; mk < 16; mk <<= 1)
#pragma unroll
      for (int rg = 0; rg < 4; ++rg) part[rg] += __shfl_xor(part[rg], mk, 16);

    if ((lane & 15) == 0) {
      const int rb = t * 16 + (lane >> 4) * 4;
#pragma unroll
      for (int rg = 0; rg < 4; ++rg) {
        const int rr = rb + rg;
        const int b2_ = (rr * 9363) >> 18;
        const int p2  = rr - b2_ * 28;
        const size_t o = (size_t)(bb0 + b2_) * 28 + p2;
        outp[o] = dmask[o] ? (part[rg] + bias3) : -1.0e9f;
      }
    }
  }
}

// ================= fallback (proven R3 fused kernel, bf16) =================
#define F_THREADS 512
#define F_NB      8
#define F_OFF_A    0
#define F_OFF_GL   16384
#define F_OFF_SB   20480
#define F_OFF_W2   53248
#define F_OFF_B1V  69632
#define F_OFF_B2V  70144
#define F_OFF_W3V  70400
#define F_SMEM     70656

__global__ __launch_bounds__(F_THREADS, 4)
void docking_fused(const float* __restrict__ node, const float* __restrict__ glob,
                   const int* __restrict__ dmask,
                   const float* __restrict__ W1, const float* __restrict__ b1,
                   const float* __restrict__ W2, const float* __restrict__ b2,
                   const float* __restrict__ W3, const float* __restrict__ b3,
                   float* __restrict__ outp)
{
  __shared__ __align__(16) char smem[F_SMEM];
  const int tid = threadIdx.x;
  const int bb0 = blockIdx.x * F_NB;
  const size_t nrow0 = (size_t)bb0 * 8;
  const float bias3 = *b3;

  if (tid < 128)      ((float*)(smem + F_OFF_B1V))[tid]       = b1[tid];
  else if (tid < 192) ((float*)(smem + F_OFF_B2V))[tid - 128] = b2[tid - 128];
  else if (tid < 256) ((float*)(smem + F_OFF_W3V))[tid - 192] = W3[tid - 192];

  for (int idx = tid; idx < 64 * 32; idx += F_THREADS) {
    const int r = idx >> 5, q = idx & 31;
    const float4 f = *(const float4*)(node + (nrow0 + (size_t)r) * 128 + q * 4);
    int2 w; w.x = (int)pkt(f.x, f.y); w.y = (int)pkt(f.z, f.w);
    *(int2*)(smem + F_OFF_A + r * 256 + ((q * 8) ^ ((r & 7) << 4))) = w;
  }
  for (int idx = tid; idx < 16 * 32; idx += F_THREADS) {
    const int r = idx >> 5, q = idx & 31;
    float4 f = make_float4(0.f, 0.f, 0.f, 0.f);
    if (r < F_NB) f = *(const float4*)(glob + (size_t)(bb0 + r) * 128 + q * 4);
    int2 w; w.x = (int)pkt(f.x, f.y); w.y = (int)pkt(f.z, f.w);
    *(int2*)(smem + F_OFF_GL + r * 256 + ((q * 8) ^ ((r & 7) << 4))) = w;
  }
  for (int idx = tid; idx < 4096; idx += F_THREADS) {
    const int cl = idx & 7, kl = (idx >> 3) & 7, ch = (idx >> 6) & 7, kh = idx >> 9;
    const int c = cl | (ch << 3), kp = kl | (kh << 3);
    const float a  = W2[(size_t)(2 * kp) * 64 + c];
    const float b_ = W2[(size_t)(2 * kp + 1) * 64 + c];
    *(unsigned*)(smem + F_OFF_W2 + c * 256 + ((kp * 4) ^ ((c & 7) << 4))) = pkt(a, b_);
  }
  auto stageB = [&](int rowOff) {
    for (int idx = tid; idx < 8192; idx += F_THREADS) {
      const int cl = idx & 7, kl = (idx >> 3) & 7, ch = (idx >> 6) & 15, kh = idx >> 10;
      const int c = cl | (ch << 3), kp = kl | (kh << 3);
      const float a  = W1[(size_t)(rowOff + 2 * kp) * 128 + c];
      const float b_ = W1[(size_t)(rowOff + 2 * kp + 1) * 128 + c];
      *(unsigned*)(smem + F_OFF_SB + c * 256 + ((kp * 4) ^ ((c & 7) << 4))) = pkt(a, b_);
    }
  };
  stageB(0);
  __syncthreads();

  const int wave = tid >> 6, lane = tid & 63;
  const int lrow = lane & 15;
  const int lko  = (lane >> 4) * 8;
  const int wmt = wave >> 1, wnh = wave & 1;
  const v4f vzero = {0.f, 0.f, 0.f, 0.f};

  bf16x8 af[4];
#pragma unroll
  for (int ks = 0; ks < 4; ++ks) {
    const int r = wmt * 16 + lrow;
    af[ks] = *(const bf16x8*)(smem + F_OFF_A + r * 256 + (((ks * 32 + lko) * 2) ^ ((r & 7) << 4)));
  }
  v4f acc_a[4] = {vzero, vzero, vzero, vzero};
#pragma unroll
  for (int ks = 0; ks < 4; ++ks) {
    const int kb = (ks * 32 + lko) * 2;
#pragma unroll
    for (int nt = 0; nt < 4; ++nt) {
      const int c = wnh * 64 + nt * 16 + lrow;
      const bf16x8 bfr = *(const bf16x8*)(smem + F_OFF_SB + c * 256 + (kb ^ ((c & 7) << 4)));
      acc_a[nt] = __builtin_amdgcn_mfma_f32_16x16x32_bf16(af[ks], bfr, acc_a[nt], 0, 0, 0);
    }
  }
  __syncthreads();
  stageB(128);
  __syncthreads();
  v4f acc_b[4] = {vzero, vzero, vzero, vzero};
#pragma unroll
  for (int ks = 0; ks < 4; ++ks) {
    const int kb = (ks * 32 + lko) * 2;
#pragma unroll
    for (int nt = 0; nt < 4; ++nt) {
      const int c = wnh * 64 + nt * 16 + lrow;
      const bf16x8 bfr = *(const bf16x8*)(smem + F_OFF_SB + c * 256 + (kb ^ ((c & 7) << 4)));
      acc_b[nt] = __builtin_amdgcn_mfma_f32_16x16x32_bf16(af[ks], bfr, acc_b[nt], 0, 0, 0);
    }
  }
  __syncthreads();
  stageB(256);
  __syncthreads();
  v4f accg = vzero;
#pragma unroll
  for (int ks = 0; ks < 4; ++ks) {
    const int kb = (ks * 32 + lko) * 2;
    const bf16x8 ag = *(const bf16x8*)(smem + F_OFF_GL + lrow * 256 + (kb ^ ((lrow & 7) << 4)));
    const int cg = wave * 16 + lrow;
    const bf16x8 bg = *(const bf16x8*)(smem + F_OFF_SB + cg * 256 + (kb ^ ((cg & 7) << 4)));
    accg = __builtin_amdgcn_mfma_f32_16x16x32_bf16(ag, bg, accg, 0, 0, 0);
  }
  __syncthreads();
  {
    const int rgb = (lane >> 4) * 4;
#pragma unroll
    for (int nt = 0; nt < 4; ++nt) {
      const int c = wnh * 64 + nt * 16 + lrow;
#pragma unroll
      for (int rg = 0; rg < 4; ++rg) {
        const int m = wmt * 16 + rgb + rg;
        const int sw = (c * 2) ^ ((m & 7) << 4);
        *(u16*)(smem + F_OFF_SB + m * 256 + sw)        = (u16)(asu(acc_a[nt][rg]) >> 16);
        *(u16*)(smem + F_OFF_SB + (64 + m) * 256 + sw) = (u16)(asu(acc_b[nt][rg]) >> 16);
      }
    }
    const int cg = wave * 16 + lrow;
    const float b1c = ((const float*)(smem + F_OFF_B1V))[cg];
#pragma unroll
    for (int rg = 0; rg < 4; ++rg) {
      const int bbr = rgb + rg;
      if (bbr < F_NB)
        *(u16*)(smem + F_OFF_A + bbr * 256 + ((cg * 2) ^ ((bbr & 7) << 4))) =
            (u16)(asu(accg[rg] + b1c) >> 16);
    }
  }
  __syncthreads();

  float b2n[4], w3n[4];
#pragma unroll
  for (int nt = 0; nt < 4; ++nt) {
    const int n = nt * 16 + lrow;
    b2n[nt] = ((const float*)(smem + F_OFF_B2V))[n];
    w3n[nt] = ((const float*)(smem + F_OFF_W3V))[n];
  }
  for (int t = wave; t < 14; t += 8) {
    const int r  = t * 16 + lrow;
    const int bb = (r * 9363) >> 18;
    const int p  = r - bb * 28;
    const unsigned pr8 = c_pair[p];
    const int mi = bb * 8 + (int)(pr8 >> 3);
    const int mj = 64 + bb * 8 + (int)(pr8 & 7);
    v4f acc2[4] = {vzero, vzero, vzero, vzero};
#pragma unroll
    for (int ks = 0; ks < 4; ++ks) {
      const int kb = (ks * 32 + lko) * 2;
      const u32x4 va = *(const u32x4*)(smem + F_OFF_SB + mi * 256 + (kb ^ ((mi & 7) << 4)));
      const u32x4 vb = *(const u32x4*)(smem + F_OFF_SB + mj * 256 + (kb ^ ((mj & 7) << 4)));
      const u32x4 vg = *(const u32x4*)(smem + F_OFF_A  + bb * 256 + (kb ^ ((bb & 7) << 4)));
      u32x4 a2;
#pragma unroll
      for (int w = 0; w < 4; ++w) {
        const float lo = fmaxf(lo2f(va[w]) + lo2f(vb[w]) + lo2f(vg[w]), 0.0f);
        const float hi = fmaxf(hi2f(va[w]) + hi2f(vb[w]) + hi2f(vg[w]), 0.0f);
        a2[w] = pkt(lo, hi);
      }
      union { u32x4 u; bf16x8 h; } cv; cv.u = a2;
#pragma unroll
      for (int nt = 0; nt < 4; ++nt) {
        const int c = nt * 16 + lrow;
        const bf16x8 w2fr = *(const bf16x8*)(smem + F_OFF_W2 + c * 256 + (kb ^ ((c & 7) << 4)));
        acc2[nt] = __builtin_amdgcn_mfma_f32_16x16x32_bf16(cv.h, w2fr, acc2[nt], 0, 0, 0);
      }
    }
    float part[4] = {0.f, 0.f, 0.f, 0.f};
#pragma unroll
    for (int nt = 0; nt < 4; ++nt)
#pragma unroll
      for (int rg = 0; rg < 4; ++rg)
        part[rg] += fmaxf(acc2[nt][rg] + b2n[nt], 0.0f) * w3n[nt];
#pragma unroll
    for (int mk = 1; mk < 16; mk <<= 1)
#pragma unroll
      for (int rg = 0; rg < 4; ++rg) part[rg] += __shfl_xor(part[rg], mk, 16);
    if ((lane & 15) == 0) {
      const int rb = t * 16 + (lane >> 4) * 4;
#pragma unroll
      for (int rg = 0; rg < 4; ++rg) {
        const int rr = rb + rg;
        const int b2_ = (rr * 9363) >> 18;
        const int p2  = rr - b2_ * 28;
        const size_t o = (size_t)(bb0 + b2_) * 28 + p2;
        outp[o] = dmask[o] ? (part[rg] + bias3) : -1.0e9f;
      }
    }
  }
}

extern "C" void kernel_launch(void* const* d_in, const int* in_sizes, int n_in,
                              void* d_out, int out_size, void* d_ws, size_t ws_size,
                              hipStream_t stream) {
  (void)in_sizes; (void)n_in; (void)out_size;
  const float* node = (const float*)d_in[0];
  const float* glob = (const float*)d_in[1];
  const int* dmsk   = (const int*)d_in[3];   // bool -> int32 on upload
  const float* W1 = (const float*)d_in[5];
  const float* b1 = (const float*)d_in[6];
  const float* W2 = (const float*)d_in[7];
  const float* b2 = (const float*)d_in[8];
  const float* W3 = (const float*)d_in[9];
  const float* b3 = (const float*)d_in[10];
  float* outp = (float*)d_out;

  if (ws_size >= (size_t)WS_NEED) {
    char* ws = (char*)d_ws;
    prep_weights<<<28, 1024, 0, stream>>>(W1, W2, ws);
    prep_gp<<<128, 256, 0, stream>>>(glob, b1, ws);
    docking_main<<<2048, 512, 0, stream>>>(node, dmsk, b2, W3, b3, ws, outp);
  } else {
    docking_fused<<<16384 / F_NB, F_THREADS, 0, stream>>>(node, glob, dmsk, W1, b1, W2, b2, W3, b3, outp);
  }
}

// Round 15
// 55.362 us; speedup vs baseline: 1.2144x; 1.1384x over previous
//
#include <hip/hip_runtime.h>

typedef float    v4f    __attribute__((ext_vector_type(4)));
typedef __fp16   f16x8  __attribute__((ext_vector_type(8)));
typedef __fp16   f16x2  __attribute__((ext_vector_type(2)));
typedef short    bf16x8 __attribute__((ext_vector_type(8)));
typedef unsigned u32x4  __attribute__((ext_vector_type(4)));
typedef unsigned short u16;

__constant__ unsigned char c_pair[28] = {
  1,2,3,4,5,6,7, 10,11,12,13,14,15, 19,20,21,22,23, 28,29,30,31, 37,38,39, 46,47, 55
};

static __device__ __forceinline__ unsigned asu(float f){ union{float f;unsigned u;}v; v.f=f; return v.u; }
static __device__ __forceinline__ float lo2f(unsigned d){ union{unsigned u;float f;}v; v.u = d<<16; return v.f; }
static __device__ __forceinline__ float hi2f(unsigned d){ union{unsigned u;float f;}v; v.u = d & 0xffff0000u; return v.f; }
// bf16 pack (fallback kernel only)
static __device__ __forceinline__ unsigned pkt(float lo, float hi){
  return __builtin_amdgcn_perm(asu(hi), asu(lo), 0x07060302u);
}
// f16 pack: one v_cvt_pkrtz_f16_f32
static __device__ __forceinline__ unsigned pkh(float lo, float hi){
  union { f16x2 h; unsigned u; } v;
  v.h = __builtin_amdgcn_cvt_pkrtz(lo, hi);
  return v.u;
}

// ---------------- ws image layout (all f16, 2B elems) ----
#define WS_W1AB 0
#define WS_W1G  65536
#define WS_W2   98304
#define WS_NEED 114688

// ================= prep kernel (weights only; gp is computed in main now) ======
__global__ __launch_bounds__(1024)
void prep_weights(const float* __restrict__ W1, const float* __restrict__ W2, char* __restrict__ ws)
{
  const int idx = blockIdx.x * 1024 + threadIdx.x;   // 28 blocks * 1024 = 28672
  if (idx < 16384) {
    const int c = idx >> 6, kp = idx & 63;
    const int part = c >> 7, cc = c & 127;
    const float a  = W1[(size_t)(part * 128 + 2 * kp) * 128 + cc];
    const float b_ = W1[(size_t)(part * 128 + 2 * kp + 1) * 128 + cc];
    *(unsigned*)(ws + WS_W1AB + (size_t)c * 256 + ((kp * 4) ^ ((c & 7) << 4))) = pkh(a, b_);
  } else if (idx < 24576) {
    const int j = idx - 16384, c = j >> 6, kp = j & 63;
    const float a  = W1[(size_t)(256 + 2 * kp) * 128 + c];
    const float b_ = W1[(size_t)(256 + 2 * kp + 1) * 128 + c];
    *(unsigned*)(ws + WS_W1G + (size_t)c * 256 + ((kp * 4) ^ ((c & 7) << 4))) = pkh(a, b_);
  } else if (idx < 28672) {
    const int j = idx - 24576, c = j >> 6, kp = j & 63;
    const float a  = W2[(size_t)(2 * kp) * 64 + c];
    const float b_ = W2[(size_t)(2 * kp + 1) * 64 + c];
    *(unsigned*)(ws + WS_W2 + (size_t)c * 256 + ((kp * 4) ^ ((c & 7) << 4))) = pkh(a, b_);
  }
}

// ================= main kernel =================
// 2048 blocks x 512 threads (8 waves); each block = ONE 8-batch tile (64 node rows).
// LDS = ND/Pa OVERLAY (16K) + Pb (16K; first 4K doubles as glob tile pre-A2)
//       + gp f32 (4K) + V (1K) = 37888 B -> 4 blocks/CU (32 waves, occupancy cap).
// Barriers: (A) staging done; (A2) ND+glob reads done & gp written; (B) proj visible.
// gp = glob@W1g + b1 computed INLINE (4 extra MFMAs/wave) -> no prep_gp kernel.
#define M4_ND   0        // node f16 swz in phase 1; Pa after barrier A2
#define M4_PB   16384    // Pb'; bytes [0,4096) of it hold the glob f16 tile pre-A2
#define M4_GP   32768    // gp f32 [8][128]
#define M4_V    36864    // b1 f32[128] | b2 f32[64] | W3 f32[64]
#define M4_SMEM 37888

__global__ __launch_bounds__(512)
void docking_main(const float* __restrict__ node, const float* __restrict__ glob,
                  const int* __restrict__ dmask,
                  const float* __restrict__ b1, const float* __restrict__ b2,
                  const float* __restrict__ W3, const float* __restrict__ b3,
                  const char* __restrict__ ws, float* __restrict__ outp)
{
  __shared__ __align__(16) char smem[M4_SMEM];
  const int tid = threadIdx.x;
  const int wave = tid >> 6, lane = tid & 63, lrow = lane & 15, lko = (lane >> 4) * 8;
  const int wm = wave >> 2, wn = wave & 3;       // 2 (M-halves of 32 rows) x 4 (N)
  const int bb0 = blockIdx.x * 8;
  const float bias3 = *b3;
  const v4f vzero = {0.f, 0.f, 0.f, 0.f};
  const char* wsW  = ws + WS_W1AB;
  const char* wsWg = ws + WS_W1G;
  const char* wsW2 = ws + WS_W2;
  float* sV = (float*)(smem + M4_V);

  // ---- stage node tile (coalesced) + glob tile + consts ----
  for (int idx = tid; idx < 64 * 32; idx += 512) {       // 4 iters
    const int r = idx >> 5, q = idx & 31;
    const float4 f = *(const float4*)(node + ((size_t)bb0 * 8 + r) * 128 + q * 4);
    int2 w; w.x = (int)pkh(f.x, f.y); w.y = (int)pkh(f.z, f.w);
    *(int2*)(smem + M4_ND + r * 256 + ((q * 8) ^ ((r & 7) << 4))) = w;
  }
  {
    const int r = tid >> 5, q = tid & 31;                // 16 rows x 32 q (1 iter)
    float4 f = make_float4(0.f, 0.f, 0.f, 0.f);
    if (r < 8) f = *(const float4*)(glob + ((size_t)bb0 + r) * 128 + q * 4);
    int2 w; w.x = (int)pkh(f.x, f.y); w.y = (int)pkh(f.z, f.w);
    *(int2*)(smem + M4_PB + r * 256 + ((q * 8) ^ ((r & 7) << 4))) = w;
  }
  if (tid < 128)      sV[tid] = b1[tid];
  else if (tid < 192) sV[64 + tid] = b2[tid - 128];      // sV[192..255] = b2
  else if (tid < 256) sV[64 + tid] = W3[tid - 192];      // sV[256..319] = W3
  __syncthreads();                                   // (A) staging visible

  // ---- phase 1a: proj GEMM; operands SWAPPED (acc rows=c, cols=m) ----
  v4f acc[2][4];
#pragma unroll
  for (int mt = 0; mt < 2; ++mt)
#pragma unroll
    for (int nt = 0; nt < 4; ++nt) acc[mt][nt] = vzero;

#pragma unroll
  for (int ks = 0; ks < 4; ++ks) {
    const int kb = (ks * 32 + lko) * 2;
    f16x8 Bf[4];
#pragma unroll
    for (int nt = 0; nt < 4; ++nt) {
      const int c = wn * 64 + nt * 16 + lrow;
      Bf[nt] = *(const f16x8*)(wsW + c * 256 + (kb ^ ((c & 7) << 4)));
    }
#pragma unroll
    for (int mt = 0; mt < 2; ++mt) {
      const int rr = wm * 32 + mt * 16 + lrow;
      const f16x8 Af = *(const f16x8*)(smem + M4_ND + rr * 256 + (kb ^ ((rr & 7) << 4)));
#pragma unroll
      for (int nt = 0; nt < 4; ++nt)
        acc[mt][nt] = __builtin_amdgcn_mfma_f32_16x16x32_f16(Bf[nt], Af, acc[mt][nt], 0, 0, 0);
    }
  }
  // ---- phase 1b: gp = glob@W1g (unswapped; 4 MFMAs; wave owns 16 cols) ----
  {
    v4f accg = vzero;
#pragma unroll
    for (int ks = 0; ks < 4; ++ks) {
      const int kb = (ks * 32 + lko) * 2;
      const f16x8 ag = *(const f16x8*)(smem + M4_PB + lrow * 256 + (kb ^ ((lrow & 7) << 4)));
      const int cg = wave * 16 + lrow;
      const f16x8 bg = *(const f16x8*)(wsWg + cg * 256 + (kb ^ ((cg & 7) << 4)));
      accg = __builtin_amdgcn_mfma_f32_16x16x32_f16(ag, bg, accg, 0, 0, 0);
    }
    const int cg = wave * 16 + lrow;
    const float b1c = sV[cg];
    const int q0 = (lane >> 4) * 4;
    if (q0 < 8) {
#pragma unroll
      for (int rg = 0; rg < 4; ++rg)
        ((float*)(smem + M4_GP))[(q0 + rg) * 128 + cg] = accg[rg] + b1c;
    }
  }
  __syncthreads();                                   // (A2) ND/glob reads done, gp ready

  // ---- proj writes: Pa OVERLAYS ND; Pb waves fold gp ----
#pragma unroll
  for (int mt = 0; mt < 2; ++mt) {
    const int m = wm * 32 + mt * 16 + lrow;
#pragma unroll
    for (int nt = 0; nt < 4; ++nt) {
      const int cb = (wn & 1) * 64 + nt * 16 + (lane >> 4) * 4;
      float v0 = acc[mt][nt][0], v1 = acc[mt][nt][1];
      float v2 = acc[mt][nt][2], v3 = acc[mt][nt][3];
      if (wn >= 2) {
        const float4 g = *(const float4*)((const float*)(smem + M4_GP) + (m >> 3) * 128 + cb);
        v0 += g.x; v1 += g.y; v2 += g.z; v3 += g.w;
      }
      int2 w; w.x = (int)pkh(v0, v1); w.y = (int)pkh(v2, v3);
      const int pb = (wn >= 2) ? M4_PB : M4_ND;
      *(int2*)(smem + pb + m * 256 + ((cb * 2) ^ ((m & 7) << 4))) = w;
    }
  }
  __syncthreads();                                   // (B) Pa/Pb' visible

  // ---- phase 2: pair MLP; W2 fragments straight from L2 ----
  for (int t = wave; t < 14; t += 8) {
    const int r  = t * 16 + lrow;                    // 0..223
    const int bb = (r * 9363) >> 18;                 // r/28 for r<2340
    const int p  = r - bb * 28;
    const unsigned pr8 = c_pair[p];
    const int mi = bb * 8 + (int)(pr8 >> 3);
    const int mj = bb * 8 + (int)(pr8 & 7);

    v4f acc2[4] = {vzero, vzero, vzero, vzero};
#pragma unroll
    for (int ks = 0; ks < 4; ++ks) {
      const int kb = (ks * 32 + lko) * 2;
      const f16x8 va = *(const f16x8*)(smem + M4_ND + mi * 256 + (kb ^ ((mi & 7) << 4)));
      const f16x8 vb = *(const f16x8*)(smem + M4_PB + mj * 256 + (kb ^ ((mj & 7) << 4)));
      f16x8 h1 = va + vb;                                        // v_pk_add_f16
      h1 = __builtin_elementwise_max(h1, (f16x8)(__fp16)0.0f);   // v_pk_max_f16
#pragma unroll
      for (int nt = 0; nt < 4; ++nt) {
        const int cc = nt * 16 + lrow;
        const f16x8 w2fr = *(const f16x8*)(wsW2 + cc * 256 + (kb ^ ((cc & 7) << 4)));
        acc2[nt] = __builtin_amdgcn_mfma_f32_16x16x32_f16(h1, w2fr, acc2[nt], 0, 0, 0);
      }
    }
    float part[4] = {0.f, 0.f, 0.f, 0.f};
#pragma unroll
    for (int nt = 0; nt < 4; ++nt) {
      const int n = nt * 16 + lrow;
      const float b2v = sV[192 + n], w3v = sV[256 + n];
#pragma unroll
      for (int rg = 0; rg < 4; ++rg)
        part[rg] += fmaxf(acc2[nt][rg] + b2v, 0.0f) * w3v;
    }
#pragma unroll
    for (int mk = 1; mk < 16; mk <<= 1)
#pragma unroll
      for (int rg = 0; rg < 4; ++rg) part[rg] += __shfl_xor(part[rg], mk, 16);

    if ((lane & 15) == 0) {
      const int rb = t * 16 + (lane >> 4) * 4;
#pragma unroll
      for (int rg = 0; rg < 4; ++rg) {
        const int rr = rb + rg;
        const int b2_ = (rr * 9363) >> 18;
        const int p2  = rr - b2_ * 28;
        const size_t o = (size_t)(bb0 + b2_) * 28 + p2;
        outp[o] = dmask[o] ? (part[rg] + bias3) : -1.0e9f;
      }
    }
  }
}

// ================= fallback (proven R3 fused kernel, bf16) =================
#define F_THREADS 512
#define F_NB      8
#define F_OFF_A    0
#define F_OFF_GL   16384
#define F_OFF_SB   20480
#define F_OFF_W2   53248
#define F_OFF_B1V  69632
#define F_OFF_B2V  70144
#define F_OFF_W3V  70400
#define F_SMEM     70656

__global__ __launch_bounds__(F_THREADS, 4)
void docking_fused(const float* __restrict__ node, const float* __restrict__ glob,
                   const int* __restrict__ dmask,
                   const float* __restrict__ W1, const float* __restrict__ b1,
                   const float* __restrict__ W2, const float* __restrict__ b2,
                   const float* __restrict__ W3, const float* __restrict__ b3,
                   float* __restrict__ outp)
{
  __shared__ __align__(16) char smem[F_SMEM];
  const int tid = threadIdx.x;
  const int bb0 = blockIdx.x * F_NB;
  const size_t nrow0 = (size_t)bb0 * 8;
  const float bias3 = *b3;

  if (tid < 128)      ((float*)(smem + F_OFF_B1V))[tid]       = b1[tid];
  else if (tid < 192) ((float*)(smem + F_OFF_B2V))[tid - 128] = b2[tid - 128];
  else if (tid < 256) ((float*)(smem + F_OFF_W3V))[tid - 192] = W3[tid - 192];

  for (int idx = tid; idx < 64 * 32; idx += F_THREADS) {
    const int r = idx >> 5, q = idx & 31;
    const float4 f = *(const float4*)(node + (nrow0 + (size_t)r) * 128 + q * 4);
    int2 w; w.x = (int)pkt(f.x, f.y); w.y = (int)pkt(f.z, f.w);
    *(int2*)(smem + F_OFF_A + r * 256 + ((q * 8) ^ ((r & 7) << 4))) = w;
  }
  for (int idx = tid; idx < 16 * 32; idx += F_THREADS) {
    const int r = idx >> 5, q = idx & 31;
    float4 f = make_float4(0.f, 0.f, 0.f, 0.f);
    if (r < F_NB) f = *(const float4*)(glob + (size_t)(bb0 + r) * 128 + q * 4);
    int2 w; w.x = (int)pkt(f.x, f.y); w.y = (int)pkt(f.z, f.w);
    *(int2*)(smem + F_OFF_GL + r * 256 + ((q * 8) ^ ((r & 7) << 4))) = w;
  }
  for (int idx = tid; idx < 4096; idx += F_THREADS) {
    const int cl = idx & 7, kl = (idx >> 3) & 7, ch = (idx >> 6) & 7, kh = idx >> 9;
    const int c = cl | (ch << 3), kp = kl | (kh << 3);
    const float a  = W2[(size_t)(2 * kp) * 64 + c];
    const float b_ = W2[(size_t)(2 * kp + 1) * 64 + c];
    *(unsigned*)(smem + F_OFF_W2 + c * 256 + ((kp * 4) ^ ((c & 7) << 4))) = pkt(a, b_);
  }
  auto stageB = [&](int rowOff) {
    for (int idx = tid; idx < 8192; idx += F_THREADS) {
      const int cl = idx & 7, kl = (idx >> 3) & 7, ch = (idx >> 6) & 15, kh = idx >> 10;
      const int c = cl | (ch << 3), kp = kl | (kh << 3);
      const float a  = W1[(size_t)(rowOff + 2 * kp) * 128 + c];
      const float b_ = W1[(size_t)(rowOff + 2 * kp + 1) * 128 + c];
      *(unsigned*)(smem + F_OFF_SB + c * 256 + ((kp * 4) ^ ((c & 7) << 4))) = pkt(a, b_);
    }
  };
  stageB(0);
  __syncthreads();

  const int wave = tid >> 6, lane = tid & 63;
  const int lrow = lane & 15;
  const int lko  = (lane >> 4) * 8;
  const int wmt = wave >> 1, wnh = wave & 1;
  const v4f vzero = {0.f, 0.f, 0.f, 0.f};

  bf16x8 af[4];
#pragma unroll
  for (int ks = 0; ks < 4; ++ks) {
    const int r = wmt * 16 + lrow;
    af[ks] = *(const bf16x8*)(smem + F_OFF_A + r * 256 + (((ks * 32 + lko) * 2) ^ ((r & 7) << 4)));
  }
  v4f acc_a[4] = {vzero, vzero, vzero, vzero};
#pragma unroll
  for (int ks = 0; ks < 4; ++ks) {
    const int kb = (ks * 32 + lko) * 2;
#pragma unroll
    for (int nt = 0; nt < 4; ++nt) {
      const int c = wnh * 64 + nt * 16 + lrow;
      const bf16x8 bfr = *(const bf16x8*)(smem + F_OFF_SB + c * 256 + (kb ^ ((c & 7) << 4)));
      acc_a[nt] = __builtin_amdgcn_mfma_f32_16x16x32_bf16(af[ks], bfr, acc_a[nt], 0, 0, 0);
    }
  }
  __syncthreads();
  stageB(128);
  __syncthreads();
  v4f acc_b[4] = {vzero, vzero, vzero, vzero};
#pragma unroll
  for (int ks = 0; ks < 4; ++ks) {
    const int kb = (ks * 32 + lko) * 2;
#pragma unroll
    for (int nt = 0; nt < 4; ++nt) {
      const int c = wnh * 64 + nt * 16 + lrow;
      const bf16x8 bfr = *(const bf16x8*)(smem + F_OFF_SB + c * 256 + (kb ^ ((c & 7) << 4)));
      acc_b[nt] = __builtin_amdgcn_mfma_f32_16x16x32_bf16(af[ks], bfr, acc_b[nt], 0, 0, 0);
    }
  }
  __syncthreads();
  stageB(256);
  __syncthreads();
  v4f accg = vzero;
#pragma unroll
  for (int ks = 0; ks < 4; ++ks) {
    const int kb = (ks * 32 + lko) * 2;
    const bf16x8 ag = *(const bf16x8*)(smem + F_OFF_GL + lrow * 256 + (kb ^ ((lrow & 7) << 4)));
    const int cg = wave * 16 + lrow;
    const bf16x8 bg = *(const bf16x8*)(smem + F_OFF_SB + cg * 256 + (kb ^ ((cg & 7) << 4)));
    accg = __builtin_amdgcn_mfma_f32_16x16x32_bf16(ag, bg, accg, 0, 0, 0);
  }
  __syncthreads();
  {
    const int rgb = (lane >> 4) * 4;
#pragma unroll
    for (int nt = 0; nt < 4; ++nt) {
      const int c = wnh * 64 + nt * 16 + lrow;
#pragma unroll
      for (int rg = 0; rg < 4; ++rg) {
        const int m = wmt * 16 + rgb + rg;
        const int sw = (c * 2) ^ ((m & 7) << 4);
        *(u16*)(smem + F_OFF_SB + m * 256 + sw)        = (u16)(asu(acc_a[nt][rg]) >> 16);
        *(u16*)(smem + F_OFF_SB + (64 + m) * 256 + sw) = (u16)(asu(acc_b[nt][rg]) >> 16);
      }
    }
    const int cg = wave * 16 + lrow;
    const float b1c = ((const float*)(smem + F_OFF_B1V))[cg];
#pragma unroll
    for (int rg = 0; rg < 4; ++rg) {
      const int bbr = rgb + rg;
      if (bbr < F_NB)
        *(u16*)(smem + F_OFF_A + bbr * 256 + ((cg * 2) ^ ((bbr & 7) << 4))) =
            (u16)(asu(accg[rg] + b1c) >> 16);
    }
  }
  __syncthreads();

  float b2n[4], w3n[4];
#pragma unroll
  for (int nt = 0; nt < 4; ++nt) {
    const int n = nt * 16 + lrow;
    b2n[nt] = ((const float*)(smem + F_OFF_B2V))[n];
    w3n[nt] = ((const float*)(smem + F_OFF_W3V))[n];
  }
  for (int t = wave; t < 14; t += 8) {
    const int r  = t * 16 + lrow;
    const int bb = (r * 9363) >> 18;
    const int p  = r - bb * 28;
    const unsigned pr8 = c_pair[p];
    const int mi = bb * 8 + (int)(pr8 >> 3);
    const int mj = 64 + bb * 8 + (int)(pr8 & 7);
    v4f acc2[4] = {vzero, vzero, vzero, vzero};
#pragma unroll
    for (int ks = 0; ks < 4; ++ks) {
      const int kb = (ks * 32 + lko) * 2;
      const u32x4 va = *(const u32x4*)(smem + F_OFF_SB + mi * 256 + (kb ^ ((mi & 7) << 4)));
      const u32x4 vb = *(const u32x4*)(smem + F_OFF_SB + mj * 256 + (kb ^ ((mj & 7) << 4)));
      const u32x4 vg = *(const u32x4*)(smem + F_OFF_A  + bb * 256 + (kb ^ ((bb & 7) << 4)));
      u32x4 a2;
#pragma unroll
      for (int w = 0; w < 4; ++w) {
        const float lo = fmaxf(lo2f(va[w]) + lo2f(vb[w]) + lo2f(vg[w]), 0.0f);
        const float hi = fmaxf(hi2f(va[w]) + hi2f(vb[w]) + hi2f(vg[w]), 0.0f);
        a2[w] = pkt(lo, hi);
      }
      union { u32x4 u; bf16x8 h; } cv; cv.u = a2;
#pragma unroll
      for (int nt = 0; nt < 4; ++nt) {
        const int c = nt * 16 + lrow;
        const bf16x8 w2fr = *(const bf16x8*)(smem + F_OFF_W2 + c * 256 + (kb ^ ((c & 7) << 4)));
        acc2[nt] = __builtin_amdgcn_mfma_f32_16x16x32_bf16(cv.h, w2fr, acc2[nt], 0, 0, 0);
      }
    }
    float part[4] = {0.f, 0.f, 0.f, 0.f};
#pragma unroll
    for (int nt = 0; nt < 4; ++nt)
#pragma unroll
      for (int rg = 0; rg < 4; ++rg)
        part[rg] += fmaxf(acc2[nt][rg] + b2n[nt], 0.0f) * w3n[nt];
#pragma unroll
    for (int mk = 1; mk < 16; mk <<= 1)
#pragma unroll
      for (int rg = 0; rg < 4; ++rg) part[rg] += __shfl_xor(part[rg], mk, 16);
    if ((lane & 15) == 0) {
      const int rb = t * 16 + (lane >> 4) * 4;
#pragma unroll
      for (int rg = 0; rg < 4; ++rg) {
        const int rr = rb + rg;
        const int b2_ = (rr * 9363) >> 18;
        const int p2  = rr - b2_ * 28;
        const size_t o = (size_t)(bb0 + b2_) * 28 + p2;
        outp[o] = dmask[o] ? (part[rg] + bias3) : -1.0e9f;
      }
    }
  }
}

extern "C" void kernel_launch(void* const* d_in, const int* in_sizes, int n_in,
                              void* d_out, int out_size, void* d_ws, size_t ws_size,
                              hipStream_t stream) {
  (void)in_sizes; (void)n_in; (void)out_size;
  const float* node = (const float*)d_in[0];
  const float* glob = (const float*)d_in[1];
  const int* dmsk   = (const int*)d_in[3];   // bool -> int32 on upload
  const float* W1 = (const float*)d_in[5];
  const float* b1 = (const float*)d_in[6];
  const float* W2 = (const float*)d_in[7];
  const float* b2 = (const float*)d_in[8];
  const float* W3 = (const float*)d_in[9];
  const float* b3 = (const float*)d_in[10];
  float* outp = (float*)d_out;

  if (ws_size >= (size_t)WS_NEED) {
    char* ws = (char*)d_ws;
    prep_weights<<<28, 1024, 0, stream>>>(W1, W2, ws);
    docking_main<<<2048, 512, 0, stream>>>(node, glob, dmsk, b1, b2, W3, b3, ws, outp);
  } else {
    docking_fused<<<16384 / F_NB, F_THREADS, 0, stream>>>(node, glob, dmsk, W1, b1, W2, b2, W3, b3, outp);
  }
}